// Round 10
// baseline (462.516 us; speedup 1.0000x reference)
//
#include <hip/hip_runtime.h>
#include <math.h>

#define N_GT 256
#define M_PR 1024
#define LG   91
#define CPL  16   // columns per lane (contiguous: lane owns [lane*16, lane*16+16))

// f64 DPP min-reduce stage (validated CTRL/mask sequence from r8; masked
// lanes keep old -> fmin(mine,mine) identity). Value-only: ties resolved
// later by ballot + lowest-lane (= smallest column).
#define DPPMIN(red, CTRL, RM, BM) do { \
    int _rh = __double2hiint(red), _rl = __double2loint(red); \
    int _oh = __builtin_amdgcn_update_dpp(_rh, _rh, CTRL, RM, BM, false); \
    int _ol = __builtin_amdgcn_update_dpp(_rl, _rl, CTRL, RM, BM, false); \
    (red) = fmin((red), __hiloint2double(_oh, _ol)); \
} while (0)

// ---------------------------------------------------------------------------
// Kernel 1: cost[i][j] = sqrt(|cgt_i - cpred_j|^2) + sum_l |lgt_i - lpred_j|
// F64=1 stores the f32 value widened to double (bit-identical semantics).
// Fused rowmin/rowarg (first-occurrence argmin) for the greedy init.
// ---------------------------------------------------------------------------
template<int F64>
__global__ __launch_bounds__(256) void cost_kernel(
    const float* __restrict__ cgt, const float* __restrict__ cpred,
    const float* __restrict__ lgt, const float* __restrict__ lpred,
    void* __restrict__ costout, float* __restrict__ rowmin, int* __restrict__ rowarg)
{
    __shared__ float sg[LG];
    __shared__ float gx, gy;
    __shared__ float wmin[4];
    __shared__ int   warg[4];
    const int i   = blockIdx.x;
    const int tid = threadIdx.x;
    if (tid < LG) sg[tid] = lgt[i * LG + tid];
    if (tid == 0) { gx = cgt[2 * i]; gy = cgt[2 * i + 1]; }
    __syncthreads();
    float bv = 1e30f; int bj = 0;
    for (int j = tid; j < M_PR; j += 256) {
        float dx = gx - cpred[2 * j];
        float dy = gy - cpred[2 * j + 1];
        float cd = sqrtf(dx * dx + dy * dy);
        const float* lp = lpred + j * LG;
        float s = 0.f;
        #pragma unroll 7
        for (int l = 0; l < LG; ++l) s += fabsf(sg[l] - lp[l]);
        float cv = cd + s;
        if (F64) ((double*)costout)[(size_t)i * M_PR + j] = (double)cv;
        else     ((float*) costout)[(size_t)i * M_PR + j] = cv;
        if (cv < bv) { bv = cv; bj = j; }
    }
    const int lane = tid & 63, wid = tid >> 6;
    #pragma unroll
    for (int off = 1; off < 64; off <<= 1) {
        float ov = __shfl_xor(bv, off, 64);
        int   oj = __shfl_xor(bj, off, 64);
        if (ov < bv || (ov == bv && oj < bj)) { bv = ov; bj = oj; }
    }
    if (lane == 0) { wmin[wid] = bv; warg[wid] = bj; }
    __syncthreads();
    if (tid == 0) {
        for (int w = 1; w < 4; ++w)
            if (wmin[w] < bv || (wmin[w] == bv && warg[w] < bj)) { bv = wmin[w]; bj = warg[w]; }
        rowmin[i] = bv; rowarg[i] = bj;
    }
}

// ---------------------------------------------------------------------------
// Kernel 2: JV LSA (r8/r9-validated semantics: greedy claim u=rowmin, v=0,
// then exact Dijkstra per unmatched row). Single wave, zero barriers in the
// inner loop. This round: split tournament (old-A part hidden under the row
// load latency; cur part gated on strict improvement, parent=j0 uniform),
// value-only f64 DPP min reduce + ballot/lowest-lane winner (exact smallest-
// col tie-break via contiguous lane->column ownership), register-resident p
// replica for the hot p[j1] broadcast. v-poison (-inf) marks settled cols;
// markD/vsave side-state in LDS; deferred dual flush; parallel augment.
// Output (f32): [0..255]=row, [256..511]=col, [512]=cost.
// ---------------------------------------------------------------------------
template<int F64>
__global__ __launch_bounds__(64) void lsa_kernel(
    const void* __restrict__ costv,
    const float* __restrict__ rowmin, const int* __restrict__ rowarg,
    const float* __restrict__ cgt, const float* __restrict__ cpred,
    float* __restrict__ out)
{
    __shared__ double u[N_GT + 1];
    __shared__ double markD_lds[M_PR + 1];
    __shared__ double vsave_lds[M_PR + 1];
    __shared__ int    p[M_PR + 1];
    __shared__ int    pmin[M_PR + 1];
    __shared__ int    way[M_PR + 1];
    __shared__ int    pathbuf[N_GT + 8];
    __shared__ int    pathlen_s;
    __shared__ int    freeA[N_GT];
    __shared__ int    colarr[N_GT];

    const int lane = threadIdx.x;
    const double NEGINF = -__builtin_inf();
    const double INFD   =  __builtin_inf();

    double v[CPL], A[CPL];
    int    bw[CPL], p_reg[CPL];

    const int      colbase = lane * CPL;                 // 0-based first owned col
    const unsigned cwbase  = (unsigned)(colbase + 1) << 11;

    for (int j = lane; j <= M_PR; j += 64) { p[j] = 0; pmin[j] = 0x7FFFFFFF; }
    for (int r = lane; r < N_GT; r += 64) colarr[r] = 0;
    if (lane == 0) u[0] = 0.0;
    #pragma unroll
    for (int k = 0; k < CPL; ++k) { v[k] = 0.0; bw[k] = 0; }
    __syncthreads();

    // ---- greedy claim: row -> its argmin col, smallest row wins ----
    #pragma unroll
    for (int g = 0; g < 4; ++g) {
        int i = g * 64 + lane;                 // 0-based row
        u[i + 1] = (double)rowmin[i];
        atomicMin(&pmin[rowarg[i] + 1], i + 1);
    }
    __syncthreads();
    for (int j = lane + 1; j <= M_PR; j += 64)
        p[j] = (pmin[j] == 0x7FFFFFFF) ? 0 : pmin[j];
    int nfree = 0;
    #pragma unroll
    for (int g = 0; g < 4; ++g) {
        int i = g * 64 + lane;
        bool um = (pmin[rowarg[i] + 1] != i + 1);
        unsigned long long mask = __ballot(um);
        int pos = nfree + __popcll(mask & ((1ull << lane) - 1ull));
        if (um) freeA[pos] = i + 1;            // 1-based row
        nfree += __popcll(mask);
    }
    __syncthreads();
    #pragma unroll
    for (int k = 0; k < CPL; ++k) p_reg[k] = p[colbase + k + 1];

    // ---- shortest augmenting path per free row ----
    for (int t = 0; t < nfree; ++t) {
        const int i = freeA[t];
        #pragma unroll
        for (int k = 0; k < CPL; ++k) A[k] = 1e18;
        unsigned usedmask = 0u;
        double D  = 0.0;
        int    j0 = 0;
        int    i0 = i;
        while (true) {
            // issue row loads first (latency hidden by settle + old tournament)
            double cd[CPL];
            if (F64) {
                const double2* rp = (const double2*)((const double*)costv
                                    + (size_t)(i0 - 1) * M_PR + colbase);
                #pragma unroll
                for (int h = 0; h < CPL / 2; ++h) {
                    double2 tv = rp[h];
                    cd[2 * h] = tv.x; cd[2 * h + 1] = tv.y;
                }
            } else {
                const float4* rp = (const float4*)((const float*)costv
                                   + (size_t)(i0 - 1) * M_PR + colbase);
                #pragma unroll
                for (int h = 0; h < CPL / 4; ++h) {
                    float4 tv = rp[h];
                    cd[4 * h]     = (double)tv.x; cd[4 * h + 1] = (double)tv.y;
                    cd[4 * h + 2] = (double)tv.z; cd[4 * h + 3] = (double)tv.w;
                }
            }
            double ui = u[i0];                  // LDS broadcast (parallel w/ loads)

            // settle previous winner j0: owner lane poisons v, saves state
            if (j0 > 0) {
                const int olane = (j0 - 1) >> 4;
                const int okk   = (j0 - 1) & 15;
                if (olane == lane) {
                    markD_lds[j0] = D;
                    #pragma unroll
                    for (int k = 0; k < CPL; ++k) {
                        if (k == okk) {
                            vsave_lds[j0] = v[k];
                            v[k] = NEGINF;      // cur = +inf henceforth
                            A[k] = INFD;        // never a candidate again
                            usedmask |= (1u << k);
                        }
                    }
                }
            }

            // old-A tournament: no load dependency -> issues in load shadow
            double   bAo  = INFD;
            unsigned bcwo = 0xFFFFFFFFu;
            #pragma unroll
            for (int k = 0; k < CPL; ++k) {
                unsigned cwk = cwbase + ((unsigned)k << 11) + (unsigned)bw[k];
                bool tk = A[k] < bAo;           // strict: smallest k kept on tie
                bAo  = tk ? A[k] : bAo;
                bcwo = tk ? cwk  : bcwo;
            }

            double base2 = ui - D;              // cur_abs = c - base2 - v[k]

            // relax + improvement-gated cur tournament (parent of any cur
            // candidate is uniformly j0; ties cur==A[k] keep OLD parent via
            // the old tournament + prefer-old merge below)
            double bAc = INFD; int bkc = 0;
            #pragma unroll
            for (int k = 0; k < CPL; ++k) {
                double cur = cd[k] - base2 - v[k];
                bool upd = (cur < A[k]);        // settled: cur=+inf -> false
                A[k]  = upd ? cur : A[k];
                bw[k] = upd ? j0  : bw[k];
                bool tk = upd && (cur < bAc);
                bAc = tk ? cur : bAc;
                bkc = tk ? k   : bkc;
            }
            // merge: prefer old candidate on exact (value, col) tie
            int      colc = colbase + bkc + 1;
            unsigned cwc  = ((unsigned)colc << 11) | (unsigned)j0;
            int      colo = (int)(bcwo >> 11);
            bool tc = (bAc < bAo) || (bAc == bAo && colc < colo);
            double   bA  = tc ? bAc : bAo;
            unsigned bcw = tc ? cwc : bcwo;

            // value-only f64 DPP min reduce -> lane 63 (validated mask seq)
            double red = bA;
            DPPMIN(red, 0x111, 0xf, 0xf);       // row_shr:1
            DPPMIN(red, 0x112, 0xf, 0xf);       // row_shr:2
            DPPMIN(red, 0x114, 0xf, 0xe);       // row_shr:4
            DPPMIN(red, 0x118, 0xf, 0xc);       // row_shr:8
            DPPMIN(red, 0x142, 0xa, 0xf);       // row_bcast:15
            DPPMIN(red, 0x143, 0xc, 0xf);       // row_bcast:31
            double Dmin = __hiloint2double(
                __builtin_amdgcn_readlane(__double2hiint(red), 63),
                __builtin_amdgcn_readlane(__double2loint(red), 63));
            // winner = lowest lane holding the min (= smallest column)
            unsigned long long mm = __ballot(bA == Dmin);
            int wl = __builtin_ctzll(mm);
            unsigned rcw = (unsigned)__builtin_amdgcn_readlane((int)bcw, wl);
            D = Dmin;
            int j1 = (int)(rcw >> 11);
            int w1 = (int)(rcw & 2047u);
            if (lane == 0) way[j1] = w1;
            // p[j1] via register replica: 4-level static select + readlane
            const int k1  = (j1 - 1) & 15;
            const int ol2 = (j1 - 1) >> 4;
            int s1_[8];
            #pragma unroll
            for (int h = 0; h < 8; ++h) s1_[h] = (k1 & 1) ? p_reg[2*h+1] : p_reg[2*h];
            int s2_[4];
            #pragma unroll
            for (int h = 0; h < 4; ++h) s2_[h] = (k1 & 2) ? s1_[2*h+1] : s1_[2*h];
            int s3_[2];
            #pragma unroll
            for (int h = 0; h < 2; ++h) s3_[h] = (k1 & 4) ? s2_[2*h+1] : s2_[2*h];
            int s4_ = (k1 & 8) ? s3_[1] : s3_[0];
            int pj = __builtin_amdgcn_readlane(s4_, ol2);
            j0 = j1;
            if (pj == 0) break;                 // reached a free column
            i0 = pj;
        }
        // ---- deferred dual flush (pre-augmentation p) ----
        if (lane == 0) u[i] += D;               // virtual col 0: markD = 0
        #pragma unroll
        for (int k = 0; k < CPL; ++k) {
            if ((usedmask >> k) & 1u) {
                const int col = colbase + k + 1;
                double adj = D - markD_lds[col];
                v[k] = vsave_lds[col] - adj;    // restore + adjust
                u[p_reg[k]] += adj;             // distinct rows, no race
            }
        }
        __syncthreads();
        // ---- augmentation: collect path, then parallel apply (old reads) ----
        if (lane == 0) {
            int L = 0, jj = j0;
            while (jj != 0) { pathbuf[L++] = jj; jj = way[jj]; }
            pathlen_s = L;
        }
        __syncthreads();
        const int L = pathlen_s;                // L <= 257
        int d0=-1,s0=0,d1=-1,s1=0,d2=-1,s2=0,d3=-1,s3=0,d4=-1,s4=0;
        { int tt = lane;       if (tt < L) { d0 = pathbuf[tt]; s0 = (tt == L-1) ? i : p[pathbuf[tt+1]]; } }
        { int tt = lane +  64; if (tt < L) { d1 = pathbuf[tt]; s1 = (tt == L-1) ? i : p[pathbuf[tt+1]]; } }
        { int tt = lane + 128; if (tt < L) { d2 = pathbuf[tt]; s2 = (tt == L-1) ? i : p[pathbuf[tt+1]]; } }
        { int tt = lane + 192; if (tt < L) { d3 = pathbuf[tt]; s3 = (tt == L-1) ? i : p[pathbuf[tt+1]]; } }
        { int tt = lane + 256; if (tt < L) { d4 = pathbuf[tt]; s4 = (tt == L-1) ? i : p[pathbuf[tt+1]]; } }
        __syncthreads();
        if (d0 >= 0) p[d0] = s0;
        if (d1 >= 0) p[d1] = s1;
        if (d2 >= 0) p[d2] = s2;
        if (d3 >= 0) p[d3] = s3;
        if (d4 >= 0) p[d4] = s4;
        __syncthreads();
        // refresh register replica of p (own cols; p writes pre-barrier)
        #pragma unroll
        for (int k = 0; k < CPL; ++k) p_reg[k] = p[colbase + k + 1];
    }

    // ---- gather + outputs (lane-stride mapping: conflict-free p reads) ----
    #pragma unroll
    for (int k = 0; k < CPL; ++k) {
        int j  = lane + 1 + 64 * k;
        int pr = p[j];
        if (pr > 0) colarr[pr - 1] = j - 1;
    }
    __syncthreads();

    for (int idx = lane; idx < N_GT; idx += 64) {
        out[idx]        = (float)idx;
        out[N_GT + idx] = (float)colarr[idx];
    }
    float s = 0.f;
    for (int idx = lane; idx < N_GT; idx += 64) {
        int c = colarr[idx];
        c = (c < 0) ? 0 : (c >= M_PR ? M_PR - 1 : c);
        float dx = cgt[2 * idx]     - cpred[2 * c];
        float dy = cgt[2 * idx + 1] - cpred[2 * c + 1];
        s += sqrtf(dx * dx + dy * dy);
    }
    #pragma unroll
    for (int off = 1; off < 64; off <<= 1) s += __shfl_xor(s, off, 64);
    if (lane == 0) out[2 * N_GT] = s;
}

extern "C" void kernel_launch(void* const* d_in, const int* in_sizes, int n_in,
                              void* d_out, int out_size, void* d_ws, size_t ws_size,
                              hipStream_t stream)
{
    const float* cgt   = (const float*)d_in[0];   // (256, 2)
    const float* cpred = (const float*)d_in[1];   // (1024, 2)
    const float* lgt   = (const float*)d_in[2];   // (256, 91)
    const float* lpred = (const float*)d_in[3];   // (1024, 91)
    float* out  = (float*)d_out;                  // 513 floats

    char* ws = (char*)d_ws;
    const size_t mat64 = (size_t)N_GT * M_PR * 8;           // 2 MB
    const size_t mat32 = (size_t)N_GT * M_PR * 4;           // 1 MB

    if (ws_size >= mat64 + 4096) {
        void*  cost   = (void*)ws;
        float* rowmin = (float*)(ws + mat64);
        int*   rowarg = (int*)  (ws + mat64 + 1024);
        cost_kernel<1><<<N_GT, 256, 0, stream>>>(cgt, cpred, lgt, lpred, cost, rowmin, rowarg);
        lsa_kernel<1><<<1, 64, 0, stream>>>(cost, rowmin, rowarg, cgt, cpred, out);
    } else {
        void*  cost   = (void*)ws;
        float* rowmin = (float*)(ws + mat32);
        int*   rowarg = (int*)  (ws + mat32 + 1024);
        cost_kernel<0><<<N_GT, 256, 0, stream>>>(cgt, cpred, lgt, lpred, cost, rowmin, rowarg);
        lsa_kernel<0><<<1, 64, 0, stream>>>(cost, rowmin, rowarg, cgt, cpred, out);
    }
}

// Round 11
// 380.470 us; speedup vs baseline: 1.2156x; 1.2156x over previous
//
#include <hip/hip_runtime.h>
#include <math.h>

#define N_GT 256
#define M_PR 1024
#define LG   91
#define CPL  16   // columns per lane (contiguous: lane owns [lane*16, lane*16+16))

// f64 DPP min-reduce stage (validated CTRL/mask sequence from r8; masked
// lanes keep old -> fmin(mine,mine) identity). Value-only: ties resolved
// later by ballot + lowest-lane (= smallest column).
#define DPPMIN(red, CTRL, RM, BM) do { \
    int _rh = __double2hiint(red), _rl = __double2loint(red); \
    int _oh = __builtin_amdgcn_update_dpp(_rh, _rh, CTRL, RM, BM, false); \
    int _ol = __builtin_amdgcn_update_dpp(_rl, _rl, CTRL, RM, BM, false); \
    (red) = fmin((red), __hiloint2double(_oh, _ol)); \
} while (0)

// ---------------------------------------------------------------------------
// Kernel 1: cost[i][j] = sqrt(|cgt_i - cpred_j|^2) + sum_l |lgt_i - lpred_j|
// F64=1 stores the f32 value widened to double (bit-identical semantics).
// Fused rowmin/rowarg (first-occurrence argmin) for the greedy init.
// ---------------------------------------------------------------------------
template<int F64>
__global__ __launch_bounds__(256) void cost_kernel(
    const float* __restrict__ cgt, const float* __restrict__ cpred,
    const float* __restrict__ lgt, const float* __restrict__ lpred,
    void* __restrict__ costout, float* __restrict__ rowmin, int* __restrict__ rowarg)
{
    __shared__ float sg[LG];
    __shared__ float gx, gy;
    __shared__ float wmin[4];
    __shared__ int   warg[4];
    const int i   = blockIdx.x;
    const int tid = threadIdx.x;
    if (tid < LG) sg[tid] = lgt[i * LG + tid];
    if (tid == 0) { gx = cgt[2 * i]; gy = cgt[2 * i + 1]; }
    __syncthreads();
    float bv = 1e30f; int bj = 0;
    for (int j = tid; j < M_PR; j += 256) {
        float dx = gx - cpred[2 * j];
        float dy = gy - cpred[2 * j + 1];
        float cd = sqrtf(dx * dx + dy * dy);
        const float* lp = lpred + j * LG;
        float s = 0.f;
        #pragma unroll 7
        for (int l = 0; l < LG; ++l) s += fabsf(sg[l] - lp[l]);
        float cv = cd + s;
        if (F64) ((double*)costout)[(size_t)i * M_PR + j] = (double)cv;
        else     ((float*) costout)[(size_t)i * M_PR + j] = cv;
        if (cv < bv) { bv = cv; bj = j; }
    }
    const int lane = tid & 63, wid = tid >> 6;
    #pragma unroll
    for (int off = 1; off < 64; off <<= 1) {
        float ov = __shfl_xor(bv, off, 64);
        int   oj = __shfl_xor(bj, off, 64);
        if (ov < bv || (ov == bv && oj < bj)) { bv = ov; bj = oj; }
    }
    if (lane == 0) { wmin[wid] = bv; warg[wid] = bj; }
    __syncthreads();
    if (tid == 0) {
        for (int w = 1; w < 4; ++w)
            if (wmin[w] < bv || (wmin[w] == bv && warg[w] < bj)) { bv = wmin[w]; bj = warg[w]; }
        rowmin[i] = bv; rowarg[i] = bj;
    }
}

// ---------------------------------------------------------------------------
// Kernel 2: JV LSA (r8/r9-validated semantics: greedy claim u=rowmin, v=0,
// then exact Dijkstra per unmatched row). Single wave, zero barriers in the
// inner loop. r11 = r10 minus the p_reg replica (its refresh was a 32-way
// LDS bank conflict, +118k conflict cycles = the r10 regression): p[j1]
// returns to the r9-proven conflict-free LDS broadcast. Kept from r10:
// contiguous-column loads (8x16B), v-poison settle, split tournament
// (old-A part issues in the load shadow), value-only f64 DPP fmin reduce
// + ballot/lowest-lane winner (exact smallest-col tie-break).
// Output (f32): [0..255]=row, [256..511]=col, [512]=cost.
// ---------------------------------------------------------------------------
template<int F64>
__global__ __launch_bounds__(64) void lsa_kernel(
    const void* __restrict__ costv,
    const float* __restrict__ rowmin, const int* __restrict__ rowarg,
    const float* __restrict__ cgt, const float* __restrict__ cpred,
    float* __restrict__ out)
{
    __shared__ double u[N_GT + 1];
    __shared__ double markD_lds[M_PR + 1];
    __shared__ double vsave_lds[M_PR + 1];
    __shared__ int    p[M_PR + 1];
    __shared__ int    pmin[M_PR + 1];
    __shared__ int    way[M_PR + 1];
    __shared__ int    pathbuf[N_GT + 8];
    __shared__ int    pathlen_s;
    __shared__ int    freeA[N_GT];
    __shared__ int    colarr[N_GT];

    const int lane = threadIdx.x;
    const double NEGINF = -__builtin_inf();
    const double INFD   =  __builtin_inf();

    double v[CPL], A[CPL];
    int    bw[CPL];

    const int      colbase = lane * CPL;                 // 0-based first owned col
    const unsigned cwbase  = (unsigned)(colbase + 1) << 11;

    for (int j = lane; j <= M_PR; j += 64) { p[j] = 0; pmin[j] = 0x7FFFFFFF; }
    for (int r = lane; r < N_GT; r += 64) colarr[r] = 0;
    if (lane == 0) u[0] = 0.0;
    #pragma unroll
    for (int k = 0; k < CPL; ++k) { v[k] = 0.0; bw[k] = 0; }
    __syncthreads();

    // ---- greedy claim: row -> its argmin col, smallest row wins ----
    #pragma unroll
    for (int g = 0; g < 4; ++g) {
        int i = g * 64 + lane;                 // 0-based row
        u[i + 1] = (double)rowmin[i];
        atomicMin(&pmin[rowarg[i] + 1], i + 1);
    }
    __syncthreads();
    for (int j = lane + 1; j <= M_PR; j += 64)
        p[j] = (pmin[j] == 0x7FFFFFFF) ? 0 : pmin[j];
    int nfree = 0;
    #pragma unroll
    for (int g = 0; g < 4; ++g) {
        int i = g * 64 + lane;
        bool um = (pmin[rowarg[i] + 1] != i + 1);
        unsigned long long mask = __ballot(um);
        int pos = nfree + __popcll(mask & ((1ull << lane) - 1ull));
        if (um) freeA[pos] = i + 1;            // 1-based row
        nfree += __popcll(mask);
    }
    __syncthreads();

    // ---- shortest augmenting path per free row ----
    for (int t = 0; t < nfree; ++t) {
        const int i = freeA[t];
        #pragma unroll
        for (int k = 0; k < CPL; ++k) A[k] = 1e18;
        unsigned usedmask = 0u;
        double D  = 0.0;
        int    j0 = 0;
        int    i0 = i;
        while (true) {
            // issue row loads first (latency hidden by settle + old tournament)
            double cd[CPL];
            if (F64) {
                const double2* rp = (const double2*)((const double*)costv
                                    + (size_t)(i0 - 1) * M_PR + colbase);
                #pragma unroll
                for (int h = 0; h < CPL / 2; ++h) {
                    double2 tv = rp[h];
                    cd[2 * h] = tv.x; cd[2 * h + 1] = tv.y;
                }
            } else {
                const float4* rp = (const float4*)((const float*)costv
                                   + (size_t)(i0 - 1) * M_PR + colbase);
                #pragma unroll
                for (int h = 0; h < CPL / 4; ++h) {
                    float4 tv = rp[h];
                    cd[4 * h]     = (double)tv.x; cd[4 * h + 1] = (double)tv.y;
                    cd[4 * h + 2] = (double)tv.z; cd[4 * h + 3] = (double)tv.w;
                }
            }
            double ui = u[i0];                  // LDS broadcast (parallel w/ loads)

            // settle previous winner j0: owner lane poisons v, saves state
            if (j0 > 0) {
                const int olane = (j0 - 1) >> 4;
                const int okk   = (j0 - 1) & 15;
                if (olane == lane) {
                    markD_lds[j0] = D;
                    #pragma unroll
                    for (int k = 0; k < CPL; ++k) {
                        if (k == okk) {
                            vsave_lds[j0] = v[k];
                            v[k] = NEGINF;      // cur = +inf henceforth
                            A[k] = INFD;        // never a candidate again
                            usedmask |= (1u << k);
                        }
                    }
                }
            }

            // old-A tournament: no load dependency -> issues in load shadow
            double   bAo  = INFD;
            unsigned bcwo = 0xFFFFFFFFu;
            #pragma unroll
            for (int k = 0; k < CPL; ++k) {
                unsigned cwk = cwbase + ((unsigned)k << 11) + (unsigned)bw[k];
                bool tk = A[k] < bAo;           // strict: smallest k kept on tie
                bAo  = tk ? A[k] : bAo;
                bcwo = tk ? cwk  : bcwo;
            }

            double base2 = ui - D;              // cur_abs = c - base2 - v[k]

            // relax + improvement-gated cur tournament (parent of any cur
            // candidate is uniformly j0; ties cur==A[k] keep OLD parent via
            // the old tournament + prefer-old merge below)
            double bAc = INFD; int bkc = 0;
            #pragma unroll
            for (int k = 0; k < CPL; ++k) {
                double cur = cd[k] - base2 - v[k];
                bool upd = (cur < A[k]);        // settled: cur=+inf -> false
                A[k]  = upd ? cur : A[k];
                bw[k] = upd ? j0  : bw[k];
                bool tk = upd && (cur < bAc);
                bAc = tk ? cur : bAc;
                bkc = tk ? k   : bkc;
            }
            // merge: prefer old candidate on exact (value, col) tie
            int      colc = colbase + bkc + 1;
            unsigned cwc  = ((unsigned)colc << 11) | (unsigned)j0;
            int      colo = (int)(bcwo >> 11);
            bool tc = (bAc < bAo) || (bAc == bAo && colc < colo);
            double   bA  = tc ? bAc : bAo;
            unsigned bcw = tc ? cwc : bcwo;

            // value-only f64 DPP min reduce -> lane 63 (validated mask seq)
            double red = bA;
            DPPMIN(red, 0x111, 0xf, 0xf);       // row_shr:1
            DPPMIN(red, 0x112, 0xf, 0xf);       // row_shr:2
            DPPMIN(red, 0x114, 0xf, 0xe);       // row_shr:4
            DPPMIN(red, 0x118, 0xf, 0xc);       // row_shr:8
            DPPMIN(red, 0x142, 0xa, 0xf);       // row_bcast:15
            DPPMIN(red, 0x143, 0xc, 0xf);       // row_bcast:31
            double Dmin = __hiloint2double(
                __builtin_amdgcn_readlane(__double2hiint(red), 63),
                __builtin_amdgcn_readlane(__double2loint(red), 63));
            // winner = lowest lane holding the min (= smallest column)
            unsigned long long mm = __ballot(bA == Dmin);
            int wl = __builtin_ctzll(mm);
            unsigned rcw = (unsigned)__builtin_amdgcn_readlane((int)bcw, wl);
            D = Dmin;
            int j1 = (int)(rcw >> 11);
            int w1 = (int)(rcw & 2047u);
            if (lane == 0) way[j1] = w1;
            int pj = p[j1];                     // LDS broadcast (conflict-free)
            j0 = j1;
            if (pj == 0) break;                 // reached a free column
            i0 = pj;
        }
        // ---- deferred dual flush (pre-augmentation p) ----
        if (lane == 0) u[i] += D;               // virtual col 0: markD = 0
        #pragma unroll
        for (int k = 0; k < CPL; ++k) {
            if ((usedmask >> k) & 1u) {
                const int col = colbase + k + 1;
                double adj = D - markD_lds[col];
                v[k] = vsave_lds[col] - adj;    // restore + adjust
                int r = p[col];                 // few active lanes, no race
                u[r] += adj;
            }
        }
        __syncthreads();
        // ---- augmentation: collect path, then parallel apply (old reads) ----
        if (lane == 0) {
            int L = 0, jj = j0;
            while (jj != 0) { pathbuf[L++] = jj; jj = way[jj]; }
            pathlen_s = L;
        }
        __syncthreads();
        const int L = pathlen_s;                // L <= 257
        int d0=-1,s0=0,d1=-1,s1=0,d2=-1,s2=0,d3=-1,s3=0,d4=-1,s4=0;
        { int tt = lane;       if (tt < L) { d0 = pathbuf[tt]; s0 = (tt == L-1) ? i : p[pathbuf[tt+1]]; } }
        { int tt = lane +  64; if (tt < L) { d1 = pathbuf[tt]; s1 = (tt == L-1) ? i : p[pathbuf[tt+1]]; } }
        { int tt = lane + 128; if (tt < L) { d2 = pathbuf[tt]; s2 = (tt == L-1) ? i : p[pathbuf[tt+1]]; } }
        { int tt = lane + 192; if (tt < L) { d3 = pathbuf[tt]; s3 = (tt == L-1) ? i : p[pathbuf[tt+1]]; } }
        { int tt = lane + 256; if (tt < L) { d4 = pathbuf[tt]; s4 = (tt == L-1) ? i : p[pathbuf[tt+1]]; } }
        __syncthreads();
        if (d0 >= 0) p[d0] = s0;
        if (d1 >= 0) p[d1] = s1;
        if (d2 >= 0) p[d2] = s2;
        if (d3 >= 0) p[d3] = s3;
        if (d4 >= 0) p[d4] = s4;
        __syncthreads();
    }

    // ---- gather + outputs (lane-stride mapping: conflict-free p reads) ----
    #pragma unroll
    for (int k = 0; k < CPL; ++k) {
        int j  = lane + 1 + 64 * k;
        int pr = p[j];
        if (pr > 0) colarr[pr - 1] = j - 1;
    }
    __syncthreads();

    for (int idx = lane; idx < N_GT; idx += 64) {
        out[idx]        = (float)idx;
        out[N_GT + idx] = (float)colarr[idx];
    }
    float s = 0.f;
    for (int idx = lane; idx < N_GT; idx += 64) {
        int c = colarr[idx];
        c = (c < 0) ? 0 : (c >= M_PR ? M_PR - 1 : c);
        float dx = cgt[2 * idx]     - cpred[2 * c];
        float dy = cgt[2 * idx + 1] - cpred[2 * c + 1];
        s += sqrtf(dx * dx + dy * dy);
    }
    #pragma unroll
    for (int off = 1; off < 64; off <<= 1) s += __shfl_xor(s, off, 64);
    if (lane == 0) out[2 * N_GT] = s;
}

extern "C" void kernel_launch(void* const* d_in, const int* in_sizes, int n_in,
                              void* d_out, int out_size, void* d_ws, size_t ws_size,
                              hipStream_t stream)
{
    const float* cgt   = (const float*)d_in[0];   // (256, 2)
    const float* cpred = (const float*)d_in[1];   // (1024, 2)
    const float* lgt   = (const float*)d_in[2];   // (256, 91)
    const float* lpred = (const float*)d_in[3];   // (1024, 91)
    float* out  = (float*)d_out;                  // 513 floats

    char* ws = (char*)d_ws;
    const size_t mat64 = (size_t)N_GT * M_PR * 8;           // 2 MB
    const size_t mat32 = (size_t)N_GT * M_PR * 4;           // 1 MB

    if (ws_size >= mat64 + 4096) {
        void*  cost   = (void*)ws;
        float* rowmin = (float*)(ws + mat64);
        int*   rowarg = (int*)  (ws + mat64 + 1024);
        cost_kernel<1><<<N_GT, 256, 0, stream>>>(cgt, cpred, lgt, lpred, cost, rowmin, rowarg);
        lsa_kernel<1><<<1, 64, 0, stream>>>(cost, rowmin, rowarg, cgt, cpred, out);
    } else {
        void*  cost   = (void*)ws;
        float* rowmin = (float*)(ws + mat32);
        int*   rowarg = (int*)  (ws + mat32 + 1024);
        cost_kernel<0><<<N_GT, 256, 0, stream>>>(cgt, cpred, lgt, lpred, cost, rowmin, rowarg);
        lsa_kernel<0><<<1, 64, 0, stream>>>(cost, rowmin, rowarg, cgt, cpred, out);
    }
}